// Round 3
// baseline (961.121 us; speedup 1.0000x reference)
//
#include <hip/hip_runtime.h>

typedef unsigned short u16;
using f32x4  = __attribute__((ext_vector_type(4))) float;
using bf16x8 = __attribute__((ext_vector_type(8))) __bf16;

// ---------- bf16 helpers ----------
__device__ __forceinline__ u16 f2bf(float f) {
  unsigned u = __builtin_bit_cast(unsigned, f);
  u += 0x7FFFu + ((u >> 16) & 1u);
  return (u16)(u >> 16);
}
__device__ __forceinline__ float bf2f(u16 h) {
  unsigned u = ((unsigned)h) << 16;
  return __builtin_bit_cast(float, u);
}

// two floats -> packed (hi bf16x2, lo bf16x2); RNE hi, trunc lo.
// residual |x - hi - lo| <= ~2^-17 |x|
__device__ __forceinline__ void split2(float f0, float f1, unsigned& hi, unsigned& lo) {
  unsigned u0 = __builtin_bit_cast(unsigned, f0);
  unsigned u1 = __builtin_bit_cast(unsigned, f1);
  unsigned r0 = u0 + (0x7FFFu + ((u0 >> 16) & 1u));
  unsigned r1 = u1 + (0x7FFFu + ((u1 >> 16) & 1u));
  hi = (r0 >> 16) | (r1 & 0xFFFF0000u);
  float h0 = __builtin_bit_cast(float, r0 & 0xFFFF0000u);
  float h1 = __builtin_bit_cast(float, r1 & 0xFFFF0000u);
  unsigned l0 = __builtin_bit_cast(unsigned, f0 - h0);
  unsigned l1 = __builtin_bit_cast(unsigned, f1 - h1);
  lo = (l0 >> 16) | (l1 & 0xFFFF0000u);
}

// ---------- split fp32 -> (bf16 hi, bf16 lo), vectorized x4 ----------
__global__ __launch_bounds__(256) void split_kernel(
    const float* __restrict__ x, u16* __restrict__ hi, u16* __restrict__ lo, int n4)
{
  const size_t t = (size_t)blockIdx.x * 256 + threadIdx.x;
  if (t >= (size_t)n4) return;
  float4 v = ((const float4*)x)[t];
  uint2 hp, lp;
  split2(v.x, v.y, hp.x, lp.x);
  split2(v.z, v.w, hp.y, lp.y);
  ((uint2*)hi)[t] = hp;
  ((uint2*)lo)[t] = lp;
}

// =====================================================================
// Fused GEMM1, LDS-less: h[:,0:512] = x1@W1^T (+b1), h[:,512:1024] = x2@W2^T (+b2)
// A (x) loaded fp32 as MFMA fragments, converted in-reg; B (W) pre-split bf16.
// split-K=2 (z) into hp0/hp1; bias added in z==0. grid (32,8,2), block 256.
// =====================================================================
__global__ __launch_bounds__(256) void gemm_h_reg(
    const float* __restrict__ x1, const float* __restrict__ x2,
    const u16* __restrict__ W1H, const u16* __restrict__ W1L,
    const u16* __restrict__ W2H, const u16* __restrict__ W2L,
    const float* __restrict__ b1, const float* __restrict__ b2,
    float* __restrict__ hp0, float* __restrict__ hp1)
{
  constexpr int K = 4096, NC = 1024, KC = 2048, BK = 32;
  const int tid  = threadIdx.x;
  const int lane = tid & 63;
  const int wave = tid >> 6;
  const int wr   = wave >> 1, wc = wave & 1;
  const int quad = lane >> 4;
  const int l16  = lane & 15;

  const int m0    = blockIdx.x * 128;
  const int n0    = blockIdx.y * 128;
  const int batch = (n0 >= 512) ? 1 : 0;
  const float* Ag = batch ? x2 : x1;
  const u16* Bh   = batch ? W2H : W1H;
  const u16* Bl   = batch ? W2L : W1L;
  const float* bias = batch ? b2 : b1;
  const int bn = n0 - batch * 512 + wc * 64;  // local col base of this wave
  const int z  = blockIdx.z;
  float* hp = z ? hp1 : hp0;
  const int k0 = z * KC + quad * 8;
  const int mb = m0 + wr * 64;

  const float* ap[4];
  const u16 *bph[4], *bpl[4];
#pragma unroll
  for (int i = 0; i < 4; ++i)
    ap[i] = Ag + (size_t)(mb + i * 16 + l16) * K + k0;
#pragma unroll
  for (int j = 0; j < 4; ++j) {
    bph[j] = Bh + (size_t)(bn + j * 16 + l16) * K + k0;
    bpl[j] = Bl + (size_t)(bn + j * 16 + l16) * K + k0;
  }

  f32x4 acc[4][4] = {};

#pragma unroll 2
  for (int kt = 0; kt < KC / BK; ++kt) {
    const int ko = kt * BK;
    bf16x8 ah[4], al[4], bh[4], bl[4];
#pragma unroll
    for (int i = 0; i < 4; ++i) {
      float4 p0 = *(const float4*)(ap[i] + ko);
      float4 p1 = *(const float4*)(ap[i] + ko + 4);
      uint4 h, l;
      split2(p0.x, p0.y, h.x, l.x); split2(p0.z, p0.w, h.y, l.y);
      split2(p1.x, p1.y, h.z, l.z); split2(p1.z, p1.w, h.w, l.w);
      ah[i] = __builtin_bit_cast(bf16x8, h);
      al[i] = __builtin_bit_cast(bf16x8, l);
    }
#pragma unroll
    for (int j = 0; j < 4; ++j) {
      bh[j] = *(const bf16x8*)(bph[j] + ko);
      bl[j] = *(const bf16x8*)(bpl[j] + ko);
    }
#pragma unroll
    for (int i = 0; i < 4; ++i)
#pragma unroll
      for (int j = 0; j < 4; ++j) {
        acc[i][j] = __builtin_amdgcn_mfma_f32_16x16x32_bf16(ah[i], bh[j], acc[i][j], 0, 0, 0);
        acc[i][j] = __builtin_amdgcn_mfma_f32_16x16x32_bf16(ah[i], bl[j], acc[i][j], 0, 0, 0);
        acc[i][j] = __builtin_amdgcn_mfma_f32_16x16x32_bf16(al[i], bh[j], acc[i][j], 0, 0, 0);
      }
  }

  // epilogue: C/D layout col=lane&15 (N), row=quad*4+reg (M)
#pragma unroll
  for (int i = 0; i < 4; ++i)
#pragma unroll
    for (int j = 0; j < 4; ++j) {
      const int gnl = bn + j * 16 + l16;          // 0..511 within batch half
      const int gn  = batch * 512 + gnl;          // 0..1023
      const float bv = (z == 0) ? bias[gnl] : 0.0f;
#pragma unroll
      for (int r = 0; r < 4; ++r) {
        const int gm = mb + i * 16 + quad * 4 + r;
        hp[(size_t)gm * NC + gn] = acc[i][j][r] + bv;
      }
    }
}

// =====================================================================
// GEMM2, LDS-less: C = S1 @ H2^T + ga ; all operands pre-split bf16.
// grid (32,32), block 256, tile 128x128, wave 64x64, K=512.
// =====================================================================
__global__ __launch_bounds__(256) void gemm2_reg(
    const u16* __restrict__ AH, const u16* __restrict__ AL,
    const u16* __restrict__ BH, const u16* __restrict__ BL,
    const float* __restrict__ ga, float* __restrict__ C)
{
  constexpr int K = 512, N = 4096;
  const int tid  = threadIdx.x;
  const int lane = tid & 63;
  const int wave = tid >> 6;
  const int wr   = wave >> 1, wc = wave & 1;
  const int quad = lane >> 4;
  const int l16  = lane & 15;

  const int mb = blockIdx.x * 128 + wr * 64;
  const int nb = blockIdx.y * 128 + wc * 64;
  const int k0 = quad * 8;

  const u16 *aph[4], *apl[4], *bph[4], *bpl[4];
#pragma unroll
  for (int i = 0; i < 4; ++i) {
    aph[i] = AH + (size_t)(mb + i * 16 + l16) * K + k0;
    apl[i] = AL + (size_t)(mb + i * 16 + l16) * K + k0;
    bph[i] = BH + (size_t)(nb + i * 16 + l16) * K + k0;
    bpl[i] = BL + (size_t)(nb + i * 16 + l16) * K + k0;
  }

  f32x4 acc[4][4] = {};

#pragma unroll 2
  for (int kt = 0; kt < K / 32; ++kt) {
    const int ko = kt * 32;
    bf16x8 ah[4], al[4], bh[4], bl[4];
#pragma unroll
    for (int i = 0; i < 4; ++i) {
      ah[i] = *(const bf16x8*)(aph[i] + ko);
      al[i] = *(const bf16x8*)(apl[i] + ko);
      bh[i] = *(const bf16x8*)(bph[i] + ko);
      bl[i] = *(const bf16x8*)(bpl[i] + ko);
    }
#pragma unroll
    for (int i = 0; i < 4; ++i)
#pragma unroll
      for (int j = 0; j < 4; ++j) {
        acc[i][j] = __builtin_amdgcn_mfma_f32_16x16x32_bf16(ah[i], bh[j], acc[i][j], 0, 0, 0);
        acc[i][j] = __builtin_amdgcn_mfma_f32_16x16x32_bf16(ah[i], bl[j], acc[i][j], 0, 0, 0);
        acc[i][j] = __builtin_amdgcn_mfma_f32_16x16x32_bf16(al[i], bh[j], acc[i][j], 0, 0, 0);
      }
  }

#pragma unroll
  for (int i = 0; i < 4; ++i)
#pragma unroll
    for (int j = 0; j < 4; ++j) {
      const int gn = nb + j * 16 + l16;
#pragma unroll
      for (int r = 0; r < 4; ++r) {
        const int gm = mb + i * 16 + quad * 4 + r;
        const size_t idx = (size_t)gm * N + gn;
        C[idx] = acc[i][j][r] + ga[idx];
      }
    }
}

// ---------- sliding-window (127) row-sum of h1 = hp0+hp1 cols [0,512) ----------
__global__ __launch_bounds__(256) void bandsum_kernel(
    const float* __restrict__ hp0, const float* __restrict__ hp1,
    u16* __restrict__ sh, u16* __restrict__ sl, int M)
{
  const int c = blockIdx.y * 256 + threadIdx.x;  // 0..511
  const int R = blockIdx.x * 128;
  float s = 0.f;
  for (int k = R - 63; k < R + 63; ++k)
    if (k >= 0 && k < M) s += hp0[(size_t)k * 1024 + c] + hp1[(size_t)k * 1024 + c];
  for (int i = R; i < R + 128; ++i) {
    const int ka = i + 63;
    if (ka < M) s += hp0[(size_t)ka * 1024 + c] + hp1[(size_t)ka * 1024 + c];
    const u16 hb = f2bf(s);
    sh[(size_t)i * 512 + c] = hb;
    sl[(size_t)i * 512 + c] = f2bf(s - bf2f(hb));
    const int kr = i - 63;
    if (kr >= 0) s -= hp0[(size_t)kr * 1024 + c] + hp1[(size_t)kr * 1024 + c];
  }
}

// ---------- h2 = hp0+hp1 cols [512,1024) -> split bf16 ----------
__global__ __launch_bounds__(256) void h2split_kernel(
    const float* __restrict__ hp0, const float* __restrict__ hp1,
    u16* __restrict__ hh, u16* __restrict__ hl)
{
  const size_t t = (size_t)blockIdx.x * 256 + threadIdx.x;
  const size_t row = t >> 7;
  const int c4 = (int)(t & 127) * 4;
  const float4 a = *(const float4*)&hp0[row * 1024 + 512 + c4];
  const float4 b = *(const float4*)&hp1[row * 1024 + 512 + c4];
  uint2 hp, lp;
  split2(a.x + b.x, a.y + b.y, hp.x, lp.x);
  split2(a.z + b.z, a.w + b.w, hp.y, lp.y);
  *(uint2*)&hh[row * 512 + c4] = hp;
  *(uint2*)&hl[row * 512 + c4] = lp;
}

// ---------- column softmax ----------
__global__ __launch_bounds__(256) void colpart_kernel(
    const float* __restrict__ lg, float* __restrict__ pm, float* __restrict__ ps,
    int M, int N, int RB)
{
  const int j  = blockIdx.x * 256 + threadIdx.x;
  const int rb = blockIdx.y;
  const int r0 = rb * RB;
  float m = -3.0e38f, s = 0.f;
  for (int i = r0; i < r0 + RB; ++i) {
    const float v = lg[(size_t)i * N + j];
    if (v <= m) {
      s += __expf(v - m);
    } else {
      s = s * __expf(m - v) + 1.0f;
      m = v;
    }
  }
  pm[(size_t)rb * N + j] = m;
  ps[(size_t)rb * N + j] = s;
}

__global__ __launch_bounds__(256) void colcombine_kernel(
    const float* __restrict__ pm, const float* __restrict__ ps,
    float* __restrict__ cv, int N, int nb)
{
  const int j = blockIdx.x * 256 + threadIdx.x;
  float m = -3.0e38f;
  for (int b = 0; b < nb; ++b) m = fmaxf(m, pm[(size_t)b * N + j]);
  float s = 0.f;
  for (int b = 0; b < nb; ++b) s += ps[(size_t)b * N + j] * __expf(pm[(size_t)b * N + j] - m);
  cv[j] = m + __logf(s);
}

__global__ __launch_bounds__(256) void norm_kernel(
    float* __restrict__ lg, const float* __restrict__ cv, int N)
{
  const size_t t = (size_t)blockIdx.x * 256 + threadIdx.x;
  float4 v = ((const float4*)lg)[t];
  const int j4 = (int)(t % (size_t)(N / 4));
  const float4 c = ((const float4*)cv)[j4];
  float4 o;
  o.x = __expf(v.x - c.x);
  o.y = __expf(v.y - c.y);
  o.z = __expf(v.z - c.z);
  o.w = __expf(v.w - c.w);
  ((float4*)lg)[t] = o;
}

extern "C" void kernel_launch(void* const* d_in, const int* in_sizes, int n_in,
                              void* d_out, int out_size, void* d_ws, size_t ws_size,
                              hipStream_t stream)
{
  const float* x1 = (const float*)d_in[0];
  const float* x2 = (const float*)d_in[1];
  const float* W1 = (const float*)d_in[2];
  const float* b1 = (const float*)d_in[3];
  const float* W2 = (const float*)d_in[4];
  const float* b2 = (const float*)d_in[5];
  const float* ga = (const float*)d_in[6];
  float* out = (float*)d_out;

  const int T = 4096, E = 512;

  // split-K partials live in d_out (dead before lg is written there)
  float* hp0 = out;                        // 4096 x 1024
  float* hp1 = out + (size_t)T * 1024;     // 4096 x 1024

  char* w = (char*)d_ws;
  u16* W1H = (u16*)w;  w += (size_t)E * T * 2;
  u16* W1L = (u16*)w;  w += (size_t)E * T * 2;
  u16* W2H = (u16*)w;  w += (size_t)E * T * 2;
  u16* W2L = (u16*)w;  w += (size_t)E * T * 2;
  u16* S1H = (u16*)w;  w += (size_t)T * E * 2;
  u16* S1L = (u16*)w;  w += (size_t)T * E * 2;
  u16* H2H = (u16*)w;  w += (size_t)T * E * 2;
  u16* H2L = (u16*)w;  w += (size_t)T * E * 2;
  float* pm = (float*)w; w += (size_t)32 * T * 4;
  float* ps = (float*)w; w += (size_t)32 * T * 4;
  float* cv = (float*)w; w += (size_t)T * 4;

  // pre-split W1, W2 to bf16 (hi,lo)
  split_kernel<<<E * T / 1024, 256, 0, stream>>>(W1, W1H, W1L, E * T / 4);
  split_kernel<<<E * T / 1024, 256, 0, stream>>>(W2, W2H, W2L, E * T / 4);

  // h1|h2 (4096 x 1024) split-K partials, LDS-less
  gemm_h_reg<<<dim3(T / 128, 8, 2), 256, 0, stream>>>(
      x1, x2, W1H, W1L, W2H, W2L, b1, b2, hp0, hp1);

  // S1 = band-sum(h1) -> split; h2 -> split
  bandsum_kernel<<<dim3(T / 128, 2), 256, 0, stream>>>(hp0, hp1, S1H, S1L, T);
  h2split_kernel<<<T * (E / 4) / 256, 256, 0, stream>>>(hp0, hp1, H2H, H2L);

  // lg = S1 @ h2^T + global_att (into d_out), LDS-less
  gemm2_reg<<<dim3(T / 128, T / 128), 256, 0, stream>>>(
      S1H, S1L, H2H, H2L, ga, out);

  // softmax over axis 0
  colpart_kernel<<<dim3(T / 256, 32), 256, 0, stream>>>(out, pm, ps, T, T, 128);
  colcombine_kernel<<<T / 256, 256, 0, stream>>>(pm, ps, cv, T, 32);
  norm_kernel<<<T * T / 1024, 256, 0, stream>>>(out, cv, T);
}

// Round 4
// 587.282 us; speedup vs baseline: 1.6366x; 1.6366x over previous
//
#include <hip/hip_runtime.h>

typedef unsigned short u16;
using f32x4  = __attribute__((ext_vector_type(4))) float;
using bf16x8 = __attribute__((ext_vector_type(8))) __bf16;

// ---------- bf16 helpers ----------
__device__ __forceinline__ u16 f2bf(float f) {
  unsigned u = __builtin_bit_cast(unsigned, f);
  u += 0x7FFFu + ((u >> 16) & 1u);
  return (u16)(u >> 16);
}
__device__ __forceinline__ float bf2f(u16 h) {
  unsigned u = ((unsigned)h) << 16;
  return __builtin_bit_cast(float, u);
}

// two floats -> packed (hi bf16x2, lo bf16x2); RNE hi, trunc lo.
// residual |x - hi - lo| <= ~2^-17 |x|   (layout verified R1-R3)
__device__ __forceinline__ void split2(float f0, float f1, unsigned& hi, unsigned& lo) {
  unsigned u0 = __builtin_bit_cast(unsigned, f0);
  unsigned u1 = __builtin_bit_cast(unsigned, f1);
  unsigned r0 = u0 + (0x7FFFu + ((u0 >> 16) & 1u));
  unsigned r1 = u1 + (0x7FFFu + ((u1 >> 16) & 1u));
  hi = (r0 >> 16) | (r1 & 0xFFFF0000u);
  float h0 = __builtin_bit_cast(float, r0 & 0xFFFF0000u);
  float h1 = __builtin_bit_cast(float, r1 & 0xFFFF0000u);
  unsigned l0 = __builtin_bit_cast(unsigned, f0 - h0);
  unsigned l1 = __builtin_bit_cast(unsigned, f1 - h1);
  lo = (l0 >> 16) | (l1 & 0xFFFF0000u);
}

// async global->LDS, 16B/lane; LDS dest MUST be wave-uniform base + lane*16
__device__ __forceinline__ void gload_lds16(const void* g, void* l) {
  __builtin_amdgcn_global_load_lds((__attribute__((address_space(1))) void*)g,
                                   (__attribute__((address_space(3))) void*)l,
                                   16, 0, 0);
}

// ---------- split fp32 -> (bf16 hi, bf16 lo), vectorized x4 (for W) ----------
__global__ __launch_bounds__(256) void split_kernel(
    const float* __restrict__ x, u16* __restrict__ hi, u16* __restrict__ lo, int n4)
{
  const size_t t = (size_t)blockIdx.x * 256 + threadIdx.x;
  if (t >= (size_t)n4) return;
  float4 v = ((const float4*)x)[t];
  uint2 hp, lp;
  split2(v.x, v.y, hp.x, lp.x);
  split2(v.z, v.w, hp.y, lp.y);
  ((uint2*)hi)[t] = hp;
  ((uint2*)lo)[t] = lp;
}

// =====================================================================
// GEMM1: h[:,0:512]=x1@W1^T+b1, h[:,512:1024]=x2@W2^T+b2 (W stacked 1024xK)
// A staged raw fp32 via global_load_lds (src-chunk XOR swizzle), converted
// to (hi,lo) bf16 after ds_read; B pre-split bf16 staged likewise.
// 3 MFMA products per staged tile. split-K=4 -> hp0..hp3.
// grid (32, 8, 4), block 256. LDS = 32 KB.
// =====================================================================
__global__ __launch_bounds__(256) void gemm1_k(
    const float* __restrict__ x1, const float* __restrict__ x2,
    const u16* __restrict__ WH, const u16* __restrict__ WL,
    const float* __restrict__ b1, const float* __restrict__ b2,
    float* __restrict__ hp0, float* __restrict__ hp1,
    float* __restrict__ hp2, float* __restrict__ hp3)
{
  constexpr int K = 4096, NC = 1024, KC = 1024;
  __shared__ __align__(16) float lA[128 * 32];   // 16 KB, row=128B=8 chunks
  __shared__ __align__(16) u16 lBh[128 * 32];    // 8 KB, row=64B=4 chunks
  __shared__ __align__(16) u16 lBl[128 * 32];    // 8 KB

  const int tid  = threadIdx.x;
  const int lane = tid & 63;
  const int wave = tid >> 6;
  const int wr   = wave >> 1, wc = wave & 1;
  const int quad = lane >> 4;
  const int l16  = lane & 15;

  const int m0    = blockIdx.x * 128;
  const int n0    = blockIdx.y * 128;
  const int batch = (n0 >= 512);
  const float* Ag   = batch ? x2 : x1;
  const float* bias = batch ? b2 : b1;
  const int z = blockIdx.z;
  float* hp = (z == 0) ? hp0 : (z == 1) ? hp1 : (z == 2) ? hp2 : hp3;
  const int k00 = z * KC;

  // staging maps (LDS dest linear in tid*16 -> DMA-legal)
  const int rA = tid >> 3, cA = tid & 7;  // A: 4 rounds x 32 rows, 8 chunks/row
  const int rB = tid >> 2, cB = tid & 3;  // B: 2 rounds x 64 rows, 4 chunks/row

  f32x4 acc[4][4] = {};

  for (int kt = 0; kt < KC / 32; ++kt) {
    const int ko = k00 + kt * 32;
    __syncthreads();
#pragma unroll
    for (int t = 0; t < 4; ++t) {
      const int r  = t * 32 + rA;
      const int cs = (cA + r) & 7;                 // source-chunk swizzle
      gload_lds16(Ag + (size_t)(m0 + r) * K + ko + cs * 4,
                  (char*)lA + t * 4096 + tid * 16);
    }
#pragma unroll
    for (int t = 0; t < 2; ++t) {
      const int r  = t * 64 + rB;
      const int cs = (cB + (r >> 1)) & 3;
      gload_lds16(WH + (size_t)(n0 + r) * K + ko + cs * 8,
                  (char*)lBh + t * 4096 + tid * 16);
      gload_lds16(WL + (size_t)(n0 + r) * K + ko + cs * 8,
                  (char*)lBl + t * 4096 + tid * 16);
    }
    __syncthreads();

    bf16x8 ah[4], al[4], bh[4], bl[4];
#pragma unroll
    for (int i = 0; i < 4; ++i) {
      const int R = wr * 64 + i * 16 + l16;
      const float4 f0 = *(const float4*)&lA[R * 32 + ((2 * quad - R) & 7) * 4];
      const float4 f1 = *(const float4*)&lA[R * 32 + ((2 * quad + 1 - R) & 7) * 4];
      uint4 h, l;
      split2(f0.x, f0.y, h.x, l.x); split2(f0.z, f0.w, h.y, l.y);
      split2(f1.x, f1.y, h.z, l.z); split2(f1.z, f1.w, h.w, l.w);
      ah[i] = __builtin_bit_cast(bf16x8, h);
      al[i] = __builtin_bit_cast(bf16x8, l);
    }
#pragma unroll
    for (int j = 0; j < 4; ++j) {
      const int R = wc * 64 + j * 16 + l16;
      const int c = (quad - (R >> 1)) & 3;
      bh[j] = *(const bf16x8*)&lBh[R * 32 + c * 8];
      bl[j] = *(const bf16x8*)&lBl[R * 32 + c * 8];
    }
#pragma unroll
    for (int i = 0; i < 4; ++i)
#pragma unroll
      for (int j = 0; j < 4; ++j) {
        acc[i][j] = __builtin_amdgcn_mfma_f32_16x16x32_bf16(ah[i], bh[j], acc[i][j], 0, 0, 0);
        acc[i][j] = __builtin_amdgcn_mfma_f32_16x16x32_bf16(ah[i], bl[j], acc[i][j], 0, 0, 0);
        acc[i][j] = __builtin_amdgcn_mfma_f32_16x16x32_bf16(al[i], bh[j], acc[i][j], 0, 0, 0);
      }
  }

  // epilogue: C/D layout col=lane&15 (N), row=quad*4+reg (M)
#pragma unroll
  for (int i = 0; i < 4; ++i)
#pragma unroll
    for (int j = 0; j < 4; ++j) {
      const int gn = n0 + wc * 64 + j * 16 + l16;
      const float bv = (z == 0) ? bias[gn - batch * 512] : 0.0f;
#pragma unroll
      for (int r = 0; r < 4; ++r) {
        const int gm = m0 + wr * 64 + i * 16 + quad * 4 + r;
        hp[(size_t)gm * NC + gn] = acc[i][j][r] + bv;
      }
    }
}

// =====================================================================
// GEMM2: lg = S1 @ H2^T + ga ; all operands pre-split bf16, staged via
// global_load_lds with swizzle; 3 products per tile; K=512.
// grid (32, 32), block 256. LDS = 32 KB.
// =====================================================================
__global__ __launch_bounds__(256) void gemm2_k(
    const u16* __restrict__ AH, const u16* __restrict__ AL,
    const u16* __restrict__ BH, const u16* __restrict__ BL,
    const float* __restrict__ ga, float* __restrict__ C)
{
  constexpr int K = 512, N = 4096;
  __shared__ __align__(16) u16 lAh[128 * 32];
  __shared__ __align__(16) u16 lAl[128 * 32];
  __shared__ __align__(16) u16 lBh[128 * 32];
  __shared__ __align__(16) u16 lBl[128 * 32];

  const int tid  = threadIdx.x;
  const int lane = tid & 63;
  const int wave = tid >> 6;
  const int wr   = wave >> 1, wc = wave & 1;
  const int quad = lane >> 4;
  const int l16  = lane & 15;

  const int m0 = blockIdx.x * 128;
  const int n0 = blockIdx.y * 128;

  const int rB = tid >> 2, cB = tid & 3;

  f32x4 acc[4][4] = {};

  for (int kt = 0; kt < K / 32; ++kt) {
    const int ko = kt * 32;
    __syncthreads();
#pragma unroll
    for (int t = 0; t < 2; ++t) {
      const int r  = t * 64 + rB;
      const int cs = (cB + (r >> 1)) & 3;
      const size_t goA = (size_t)(m0 + r) * K + ko + cs * 8;
      const size_t goB = (size_t)(n0 + r) * K + ko + cs * 8;
      gload_lds16(AH + goA, (char*)lAh + t * 4096 + tid * 16);
      gload_lds16(AL + goA, (char*)lAl + t * 4096 + tid * 16);
      gload_lds16(BH + goB, (char*)lBh + t * 4096 + tid * 16);
      gload_lds16(BL + goB, (char*)lBl + t * 4096 + tid * 16);
    }
    __syncthreads();

    bf16x8 ah[4], al[4], bh[4], bl[4];
#pragma unroll
    for (int i = 0; i < 4; ++i) {
      const int R = wr * 64 + i * 16 + l16;
      const int c = (quad - (R >> 1)) & 3;
      ah[i] = *(const bf16x8*)&lAh[R * 32 + c * 8];
      al[i] = *(const bf16x8*)&lAl[R * 32 + c * 8];
    }
#pragma unroll
    for (int j = 0; j < 4; ++j) {
      const int R = wc * 64 + j * 16 + l16;
      const int c = (quad - (R >> 1)) & 3;
      bh[j] = *(const bf16x8*)&lBh[R * 32 + c * 8];
      bl[j] = *(const bf16x8*)&lBl[R * 32 + c * 8];
    }
#pragma unroll
    for (int i = 0; i < 4; ++i)
#pragma unroll
      for (int j = 0; j < 4; ++j) {
        acc[i][j] = __builtin_amdgcn_mfma_f32_16x16x32_bf16(ah[i], bh[j], acc[i][j], 0, 0, 0);
        acc[i][j] = __builtin_amdgcn_mfma_f32_16x16x32_bf16(ah[i], bl[j], acc[i][j], 0, 0, 0);
        acc[i][j] = __builtin_amdgcn_mfma_f32_16x16x32_bf16(al[i], bh[j], acc[i][j], 0, 0, 0);
      }
  }

#pragma unroll
  for (int i = 0; i < 4; ++i)
#pragma unroll
    for (int j = 0; j < 4; ++j) {
      const int gn = n0 + wc * 64 + j * 16 + l16;
#pragma unroll
      for (int r = 0; r < 4; ++r) {
        const int gm = m0 + wr * 64 + i * 16 + quad * 4 + r;
        const size_t idx = (size_t)gm * N + gn;
        C[idx] = acc[i][j][r] + ga[idx];
      }
    }
}

// ---------- sliding-window (127) row-sum of h1 = sum(hp0..3) cols [0,512) ----------
__global__ __launch_bounds__(256) void bandsum_kernel(
    const float* __restrict__ hp0, const float* __restrict__ hp1,
    const float* __restrict__ hp2, const float* __restrict__ hp3,
    u16* __restrict__ sh, u16* __restrict__ sl, int M)
{
  const int c = blockIdx.y * 256 + threadIdx.x;  // 0..511
  const int R = blockIdx.x * 128;
  float s = 0.f;
  for (int k = R - 63; k < R + 63; ++k)
    if (k >= 0 && k < M) {
      const size_t o = (size_t)k * 1024 + c;
      s += (hp0[o] + hp1[o]) + (hp2[o] + hp3[o]);
    }
  for (int i = R; i < R + 128; ++i) {
    const int ka = i + 63;
    if (ka < M) {
      const size_t o = (size_t)ka * 1024 + c;
      s += (hp0[o] + hp1[o]) + (hp2[o] + hp3[o]);
    }
    const u16 hb = f2bf(s);
    sh[(size_t)i * 512 + c] = hb;
    sl[(size_t)i * 512 + c] = f2bf(s - bf2f(hb));
    const int kr = i - 63;
    if (kr >= 0) {
      const size_t o = (size_t)kr * 1024 + c;
      s -= (hp0[o] + hp1[o]) + (hp2[o] + hp3[o]);
    }
  }
}

// ---------- h2 = sum(hp0..3) cols [512,1024) -> split bf16 ----------
__global__ __launch_bounds__(256) void h2split_kernel(
    const float* __restrict__ hp0, const float* __restrict__ hp1,
    const float* __restrict__ hp2, const float* __restrict__ hp3,
    u16* __restrict__ hh, u16* __restrict__ hl)
{
  const size_t t = (size_t)blockIdx.x * 256 + threadIdx.x;
  const size_t row = t >> 7;
  const int c4 = (int)(t & 127) * 4;
  const size_t o = row * 1024 + 512 + c4;
  const float4 a = *(const float4*)&hp0[o];
  const float4 b = *(const float4*)&hp1[o];
  const float4 d = *(const float4*)&hp2[o];
  const float4 e = *(const float4*)&hp3[o];
  uint2 hp, lp;
  split2((a.x + b.x) + (d.x + e.x), (a.y + b.y) + (d.y + e.y), hp.x, lp.x);
  split2((a.z + b.z) + (d.z + e.z), (a.w + b.w) + (d.w + e.w), hp.y, lp.y);
  *(uint2*)&hh[row * 512 + c4] = hp;
  *(uint2*)&hl[row * 512 + c4] = lp;
}

// ---------- column softmax ----------
__global__ __launch_bounds__(256) void colpart_kernel(
    const float* __restrict__ lg, float* __restrict__ pm, float* __restrict__ ps,
    int M, int N, int RB)
{
  const int j  = blockIdx.x * 256 + threadIdx.x;
  const int rb = blockIdx.y;
  const int r0 = rb * RB;
  float m = -3.0e38f, s = 0.f;
  for (int i = r0; i < r0 + RB; ++i) {
    const float v = lg[(size_t)i * N + j];
    if (v <= m) {
      s += __expf(v - m);
    } else {
      s = s * __expf(m - v) + 1.0f;
      m = v;
    }
  }
  pm[(size_t)rb * N + j] = m;
  ps[(size_t)rb * N + j] = s;
}

__global__ __launch_bounds__(256) void colcombine_kernel(
    const float* __restrict__ pm, const float* __restrict__ ps,
    float* __restrict__ cv, int N, int nb)
{
  const int j = blockIdx.x * 256 + threadIdx.x;
  float m = -3.0e38f;
  for (int b = 0; b < nb; ++b) m = fmaxf(m, pm[(size_t)b * N + j]);
  float s = 0.f;
  for (int b = 0; b < nb; ++b) s += ps[(size_t)b * N + j] * __expf(pm[(size_t)b * N + j] - m);
  cv[j] = m + __logf(s);
}

__global__ __launch_bounds__(256) void norm_kernel(
    float* __restrict__ lg, const float* __restrict__ cv, int N)
{
  const size_t t = (size_t)blockIdx.x * 256 + threadIdx.x;
  float4 v = ((const float4*)lg)[t];
  const int j4 = (int)(t % (size_t)(N / 4));
  const float4 c = ((const float4*)cv)[j4];
  float4 o;
  o.x = __expf(v.x - c.x);
  o.y = __expf(v.y - c.y);
  o.z = __expf(v.z - c.z);
  o.w = __expf(v.w - c.w);
  ((float4*)lg)[t] = o;
}

extern "C" void kernel_launch(void* const* d_in, const int* in_sizes, int n_in,
                              void* d_out, int out_size, void* d_ws, size_t ws_size,
                              hipStream_t stream)
{
  const float* x1 = (const float*)d_in[0];
  const float* x2 = (const float*)d_in[1];
  const float* W1 = (const float*)d_in[2];
  const float* b1 = (const float*)d_in[3];
  const float* W2 = (const float*)d_in[4];
  const float* b2 = (const float*)d_in[5];
  const float* ga = (const float*)d_in[6];
  float* out = (float*)d_out;

  const int T = 4096, E = 512;

  // split-K=4 partials live in d_out (4 x 16 MB = 64 MB, dead before lg lands)
  float* hp0 = out;
  float* hp1 = out + (size_t)T * 1024;
  float* hp2 = out + (size_t)T * 2048;
  float* hp3 = out + (size_t)T * 3072;

  char* w = (char*)d_ws;
  u16* WH  = (u16*)w;  w += (size_t)2 * E * T * 2;   // stacked (1024 x 4096)
  u16* WL  = (u16*)w;  w += (size_t)2 * E * T * 2;
  u16* S1H = (u16*)w;  w += (size_t)T * E * 2;
  u16* S1L = (u16*)w;  w += (size_t)T * E * 2;
  u16* H2H = (u16*)w;  w += (size_t)T * E * 2;
  u16* H2L = (u16*)w;  w += (size_t)T * E * 2;
  float* pm = (float*)w; w += (size_t)32 * T * 4;
  float* ps = (float*)w; w += (size_t)32 * T * 4;
  float* cv = (float*)w; w += (size_t)T * 4;

  // pre-split W1, W2 into stacked WH/WL (rows 0-511 = W1, 512-1023 = W2)
  split_kernel<<<E * T / 1024, 256, 0, stream>>>(W1, WH, WL, E * T / 4);
  split_kernel<<<E * T / 1024, 256, 0, stream>>>(
      W2, WH + (size_t)E * T, WL + (size_t)E * T, E * T / 4);

  // h partials (4096 x 1024), split-K=4
  gemm1_k<<<dim3(T / 128, 8, 4), 256, 0, stream>>>(
      x1, x2, WH, WL, b1, b2, hp0, hp1, hp2, hp3);

  // S1 = band-sum(h1) -> split; h2 -> split
  bandsum_kernel<<<dim3(T / 128, 2), 256, 0, stream>>>(
      hp0, hp1, hp2, hp3, S1H, S1L, T);
  h2split_kernel<<<T * (E / 4) / 256, 256, 0, stream>>>(
      hp0, hp1, hp2, hp3, H2H, H2L);

  // lg = S1 @ h2^T + global_att (into d_out, overwrites dead partials)
  gemm2_k<<<dim3(T / 128, T / 128), 256, 0, stream>>>(
      S1H, S1L, H2H, H2L, ga, out);

  // softmax over axis 0
  colpart_kernel<<<dim3(T / 256, 32), 256, 0, stream>>>(out, pm, ps, T, T, 128);
  colcombine_kernel<<<T / 256, 256, 0, stream>>>(pm, ps, cv, T, 32);
  norm_kernel<<<T * T / 1024, 256, 0, stream>>>(out, cv, T);
}